// Round 8
// baseline (182.035 us; speedup 1.0000x reference)
//
#include <hip/hip_runtime.h>

typedef unsigned short u16;
typedef __attribute__((ext_vector_type(8))) short bf16x8;
typedef __attribute__((ext_vector_type(4))) float f32x4;
typedef __attribute__((ext_vector_type(4))) unsigned short u16x4;
typedef __attribute__((ext_vector_type(8))) unsigned short u16x8;

#define AS1 __attribute__((address_space(1)))
#define AS3 __attribute__((address_space(3)))

__device__ __forceinline__ float b2f(u16 s) {
    return __uint_as_float(((unsigned)s) << 16);
}
__device__ __forceinline__ u16 f2b(float f) {
    unsigned u = __float_as_uint(f);
    unsigned r = 0x7fffu + ((u >> 16) & 1u);
    return (u16)((u + r) >> 16);
}

// pack hi16(p1):hi16(p0) in one v_perm_b32 (truncating bf16 convert x2)
__device__ __forceinline__ unsigned packtrunc(float p0, float p1) {
#if __has_builtin(__builtin_amdgcn_perm)
    return __builtin_amdgcn_perm(__float_as_uint(p1), __float_as_uint(p0), 0x07060302u);
#else
    return (__float_as_uint(p0) >> 16) | (__float_as_uint(p1) & 0xffff0000u);
#endif
}

// async global->LDS, 16B per lane
__device__ __forceinline__ void g2l16(const u16* g, u16* l) {
    __builtin_amdgcn_global_load_lds((const AS1 void*)g, (AS3 void*)l, 16, 0, 0);
}

#if __has_builtin(__builtin_amdgcn_exp2f)
#define EXP2(x) __builtin_amdgcn_exp2f(x)
#else
#define EXP2(x) exp2f(x)
#endif

// ---------------------------------------------------------------------------
// Kernel 1: weight prep. Three sections by blockIdx:
//  bx <  576 : G[which*64+r][h*64+d] = W1[h,r]*W2[d,r]           (192 x 768)
//  576..587  : Mqk[h*64+r1][r2] = qs * sum_d W0q[h*64+d,r1]*W0k[h*64+d,r2]
//              (64x64 per head; folds q/k expansion + 0.125*log2e scale)
//  bx >= 588 : Dcat[m][h*64+r] = sum_d PW[m,h*64+d]*Wv0[h*64+d,r] (proj+W0v)
// ---------------------------------------------------------------------------
__global__ __launch_bounds__(256) void build_prep(
    const float* __restrict__ Wq0, const float* __restrict__ Wq1, const float* __restrict__ Wq2,
    const float* __restrict__ Wk0, const float* __restrict__ Wk1, const float* __restrict__ Wk2,
    const float* __restrict__ Wv0, const float* __restrict__ Wv1, const float* __restrict__ Wv2,
    const float* __restrict__ PW,
    u16* __restrict__ G, u16* __restrict__ Mqkb, u16* __restrict__ Dcat)
{
    const int bx = blockIdx.x;
    const int t = threadIdx.x;
    if (bx < 576) {
        const int idx = bx * 256 + t;           // < 147456
        const int row = idx / 768, c = idx - row * 768;
        const int which = row >> 6, r = row & 63;
        const int h = c >> 6, d = c & 63;
        const float* W1 = (which == 0) ? Wq1 : (which == 1) ? Wk1 : Wv1;
        const float* W2 = (which == 0) ? Wq2 : (which == 1) ? Wk2 : Wv2;
        G[idx] = f2b(W1[h * 64 + r] * W2[d * 64 + r]);
    } else if (bx < 588) {
        __shared__ float wq[64 * 65];
        __shared__ float wk[64 * 65];
        const int h = bx - 576;
        const float qs = 0.125f * 1.4426950408889634f;
        for (int i = t; i < 4096; i += 256) {
            const int dd = i >> 6, r = i & 63;
            wq[dd * 65 + r] = Wq0[(h * 64 + dd) * 64 + r] * qs;
            wk[dd * 65 + r] = Wk0[(h * 64 + dd) * 64 + r];
        }
        __syncthreads();
        for (int j = t; j < 4096; j += 256) {
            const int r1 = j >> 6, r2 = j & 63;
            float acc = 0.f;
#pragma unroll
            for (int dd = 0; dd < 64; ++dd) acc += wq[dd * 65 + r1] * wk[dd * 65 + r2];
            Mqkb[(size_t)(h * 64 + r1) * 64 + r2] = f2b(acc);
        }
    } else {
        __shared__ float w0s[64 * 65];   // w0s[d][r] = Wv0[h*64+d][r]
        __shared__ float pws[32 * 65];   // pws[mi][d] = PW[mBase+mi][h*64+d]
        const int hb = bx - 588;         // 0..287
        const int h = hb / 24, mBase = (hb - h * 24) * 32;
        for (int i = t; i < 4096; i += 256) {
            const int d = i >> 6, r = i & 63;
            w0s[d * 65 + r] = Wv0[(h * 64 + d) * 64 + r];
        }
        for (int i = t; i < 2048; i += 256) {
            const int mi = i >> 6, d = i & 63;
            pws[mi * 65 + d] = PW[(size_t)(mBase + mi) * 768 + h * 64 + d];
        }
        __syncthreads();
        const int r = t & 63, mi0 = t >> 6;
        float w0c[64];
#pragma unroll
        for (int d = 0; d < 64; ++d) w0c[d] = w0s[d * 65 + r];
        for (int mi = mi0; mi < 32; mi += 4) {
            float acc = 0.f;
#pragma unroll
            for (int d = 0; d < 64; ++d) acc += pws[mi * 65 + d] * w0c[d];
            Dcat[(size_t)(mBase + mi) * 768 + h * 64 + r] = f2b(acc);
        }
    }
}

// ---------------------------------------------------------------------------
// Kernel 2: t = x(fp32) @ G^T-layout (M=8192, K=768). Grid (3,128), 64x64 tile.
// Col-tiles 0,1 (q,k parts) -> T[8192][128]; col-tile 2 (v part) -> tvt[64][8192]
// (transposed, packed 8B stores). x converted bf16 in-register during staging.
// ---------------------------------------------------------------------------
__global__ __launch_bounds__(256, 2) void gemm_t(
    const float* __restrict__ X, const u16* __restrict__ G,
    u16* __restrict__ T, u16* __restrict__ tvt)
{
    __shared__ u16 As[64 * 32];
    __shared__ u16 Bs[64 * 32];

    const int tid = threadIdx.x;
    const int lane = tid & 63, wv = tid >> 6;
    const int l15 = lane & 15, quad = lane >> 4;
    const int rowBase = blockIdx.y * 64;
    const int colBase = blockIdx.x * 64;

    const int srow = tid >> 2;          // 0..63
    const int scol = (tid & 3) * 8;     // 0/8/16/24
    const float* aS = X + (size_t)(rowBase + srow) * 768 + scol;
    const u16*  bS  = G + (size_t)(colBase + srow) * 768 + scol;

    float4 a0 = *(const float4*)(aS);
    float4 a1 = *(const float4*)(aS + 4);
    int4   b0 = *(const int4*)(bS);

    const f32x4 zero4 = {0.f, 0.f, 0.f, 0.f};
    f32x4 acc[4];
#pragma unroll
    for (int tn = 0; tn < 4; ++tn) acc[tn] = zero4;

    for (int kk = 0; kk < 768; kk += 32) {
        __syncthreads();
        u16x8 ap;
        ap[0] = f2b(a0.x); ap[1] = f2b(a0.y); ap[2] = f2b(a0.z); ap[3] = f2b(a0.w);
        ap[4] = f2b(a1.x); ap[5] = f2b(a1.y); ap[6] = f2b(a1.z); ap[7] = f2b(a1.w);
        *(u16x8*)&As[srow * 32 + scol] = ap;
        *(int4*)&Bs[srow * 32 + scol]  = b0;
        __syncthreads();

        if (kk < 736) {
            a0 = *(const float4*)(aS + kk + 32);
            a1 = *(const float4*)(aS + kk + 36);
            b0 = *(const int4*)(bS + kk + 32);
        }

        const bf16x8 af = *(const bf16x8*)(As + (wv * 16 + l15) * 32 + quad * 8);
#pragma unroll
        for (int tn = 0; tn < 4; ++tn) {
            const bf16x8 bf = *(const bf16x8*)(Bs + (tn * 16 + l15) * 32 + quad * 8);
            acc[tn] = __builtin_amdgcn_mfma_f32_16x16x32_bf16(af, bf, acc[tn], 0, 0, 0);
        }
    }

    if (colBase < 128) {
#pragma unroll
        for (int tn = 0; tn < 4; ++tn) {
            const int col = colBase + tn * 16 + l15;
#pragma unroll
            for (int r = 0; r < 4; ++r) {
                const int grow = rowBase + wv * 16 + quad * 4 + r;
                T[(size_t)grow * 128 + col] = f2b(acc[tn][r]);
            }
        }
    } else {
        // v-part: write transposed tvt[r'][token], 4 tokens packed per store
#pragma unroll
        for (int tn = 0; tn < 4; ++tn) {
            const int rr = tn * 16 + l15;                    // r index 0..63
            const int grow = rowBase + wv * 16 + quad * 4;   // token base
            u16x4 pk;
            pk.x = f2b(acc[tn][0]); pk.y = f2b(acc[tn][1]);
            pk.z = f2b(acc[tn][2]); pk.w = f2b(acc[tn][3]);
            *(u16x4*)(tvt + (size_t)rr * 8192 + grow) = pk;
        }
    }
}

// ---------------------------------------------------------------------------
// Kernel 3: k' = t_k @ Mqk_h^T  (K=64). 128x128 tiles, grid (6,64).
// Scatters k' as [bh][l][r1].
// ---------------------------------------------------------------------------
__global__ __launch_bounds__(256, 2) void gemm_expand(
    const u16* __restrict__ T, const u16* __restrict__ Mqkb, u16* __restrict__ kp)
{
    __shared__ u16 As[128 * 32];
    __shared__ u16 Bs[128 * 32];

    const int tid  = threadIdx.x;
    const int lane = tid & 63, wv = tid >> 6;
    const int l15  = lane & 15, quad = lane >> 4;
    const int rowBase = blockIdx.y * 128;
    const int colBase = blockIdx.x * 128;

    const int srow = wv * 32 + (lane >> 2);
    const int scol = (lane & 3) * 8;
    const u16* aSrc = T    + (size_t)(rowBase + srow) * 128 + 64 + scol;   // t_k part
    const u16* bSrc = Mqkb + (size_t)(colBase + srow) * 64 + scol;
    u16* aDst = As + wv * 1024;
    u16* bDst = Bs + wv * 1024;

    const f32x4 zero4 = {0.f, 0.f, 0.f, 0.f};
    f32x4 acc[4][4];
#pragma unroll
    for (int tm = 0; tm < 4; ++tm)
#pragma unroll
        for (int tn = 0; tn < 4; ++tn) acc[tm][tn] = zero4;

    const int wr = (wv >> 1) * 64, wc = (wv & 1) * 64;

    for (int kk = 0; kk < 64; kk += 32) {
        __syncthreads();
        g2l16(aSrc + kk,            aDst);
        g2l16(aSrc + kk + 16 * 128, aDst + 512);
        g2l16(bSrc + kk,            bDst);
        g2l16(bSrc + kk + 16 * 64,  bDst + 512);
        __syncthreads();

        bf16x8 af[4], bfm[4];
#pragma unroll
        for (int t = 0; t < 4; ++t) {
            af[t]  = *(const bf16x8*)(As + (wr + t * 16 + l15) * 32 + quad * 8);
            bfm[t] = *(const bf16x8*)(Bs + (wc + t * 16 + l15) * 32 + quad * 8);
        }
#pragma unroll
        for (int tm = 0; tm < 4; ++tm)
#pragma unroll
            for (int tn = 0; tn < 4; ++tn)
                acc[tm][tn] = __builtin_amdgcn_mfma_f32_16x16x32_bf16(
                    af[tm], bfm[tn], acc[tm][tn], 0, 0, 0);
    }

    const int mmBase = colBase + wc;
#pragma unroll
    for (int tm = 0; tm < 4; ++tm) {
        const int grow = rowBase + wr + tm * 16 + quad * 4;
        const int b = grow >> 10, l = grow & 1023;
#pragma unroll
        for (int tn = 0; tn < 4; ++tn) {
            const int mmv = mmBase + tn * 16 + l15;
            const int h = mmv >> 6, r1 = mmv & 63;
            const size_t base = (((size_t)(b * 12 + h) * 1024 + l) << 6) + r1;
#pragma unroll
            for (int r = 0; r < 4; ++r)
                kp[base + (size_t)r * 64] = f2b(acc[tm][tn][r]);
        }
    }
}

// ---------------------------------------------------------------------------
// Kernel 4: flash attention v7, fully in t-space. Grid (96,8): x=bh, y=qt —
// all 8 q-tiles of one bh land on the SAME XCD (96 % 8 == 0) so K'/tvt
// re-reads hit that XCD's L2. Block = 128 q rows, 4 waves x 32 q rows.
// S^T = K' x t_q^T (K' staged bit-permuted -> exits in K=32 PV A-layout);
// P truncation-packed; Z_h = P_h @ t_v; normalizer via ones-column MFMA.
// ---------------------------------------------------------------------------
__global__ __launch_bounds__(256, 3) void flash_attn7(
    const u16* __restrict__ T, const u16* __restrict__ kprime,
    const u16* __restrict__ tvt, u16* __restrict__ Z)
{
    const int bh = blockIdx.x;          // 0..95
    const int qt = blockIdx.y;          // 0..7 (128 q rows each)
    const int b = bh / 12, h = bh - b * 12;
    const u16* qp = T + ((size_t)b * 1024 + qt * 128) * 128;   // t_q rows, stride 128
    const u16* kp = kprime + (size_t)bh * 65536;
    const u16* vp = tvt + b * 1024;     // tvt[r][8192], slice cols b*1024..

    __shared__ u16 Ks[64][72];
    __shared__ u16 Vs[64][72];          // Vs[r][key]

    const int t = threadIdx.x;
    const int lane = t & 63, wv = t >> 6;
    const int l15 = lane & 15, quad = lane >> 4;

    bf16x8 qf[2][2];
#pragma unroll
    for (int qg = 0; qg < 2; ++qg) {
        const u16* qrow = qp + (size_t)(wv * 32 + qg * 16 + l15) * 128;
        qf[qg][0] = *(const bf16x8*)(qrow + quad * 8);
        qf[qg][1] = *(const bf16x8*)(qrow + 32 + quad * 8);
    }

    const int srow = t >> 2;            // key-row / r-row 0..63
    const int scol = (t & 3) * 16;
    const int p5 = srow & 31;
    const int lrow = (srow & 32) | ((p5 & 4) << 2) | ((p5 & 16) >> 1)
                   | ((p5 & 8) >> 1) | (p5 & 3);   // permuted K row

    bf16x8 vone = {};
    if (l15 == 0) {
#pragma unroll
        for (int j = 0; j < 8; ++j) vone[j] = (short)0x3F80;
    }

    int4 kr0 = *(const int4*)(kp + srow * 64 + scol);
    int4 kr1 = *(const int4*)(kp + srow * 64 + scol + 8);
    int4 vr0 = *(const int4*)(vp + (size_t)srow * 8192 + scol);
    int4 vr1 = *(const int4*)(vp + (size_t)srow * 8192 + scol + 8);

    const f32x4 zero4 = {0.f, 0.f, 0.f, 0.f};
    f32x4 o_acc[2][4];
    f32x4 Lacc[2] = {zero4, zero4};
#pragma unroll
    for (int qg = 0; qg < 2; ++qg)
#pragma unroll
        for (int tn = 0; tn < 4; ++tn) o_acc[qg][tn] = zero4;

    for (int kt = 0; kt < 16; ++kt) {
        __syncthreads();
        *(int4*)&Ks[lrow][scol]     = kr0;
        *(int4*)&Ks[lrow][scol + 8] = kr1;
        *(int4*)&Vs[srow][scol]     = vr0;
        *(int4*)&Vs[srow][scol + 8] = vr1;
        __syncthreads();

        if (kt < 15) {
            kr0 = *(const int4*)(kp + (kt + 1) * 4096 + srow * 64 + scol);
            kr1 = *(const int4*)(kp + (kt + 1) * 4096 + srow * 64 + scol + 8);
            vr0 = *(const int4*)(vp + (size_t)srow * 8192 + (kt + 1) * 64 + scol);
            vr1 = *(const int4*)(vp + (size_t)srow * 8192 + (kt + 1) * 64 + scol + 8);
        }

        // S^T = K' x t_q^T (keys permuted per tile)
        f32x4 Sacc[2][4];
#pragma unroll
        for (int qg = 0; qg < 2; ++qg)
#pragma unroll
            for (int tk = 0; tk < 4; ++tk) Sacc[qg][tk] = zero4;
#pragma unroll
        for (int ks = 0; ks < 2; ++ks) {
#pragma unroll
            for (int tk = 0; tk < 4; ++tk) {
                const bf16x8 kf = *(const bf16x8*)&Ks[tk * 16 + l15][ks * 32 + quad * 8];
                Sacc[0][tk] = __builtin_amdgcn_mfma_f32_16x16x32_bf16(kf, qf[0][ks], Sacc[0][tk], 0, 0, 0);
                Sacc[1][tk] = __builtin_amdgcn_mfma_f32_16x16x32_bf16(kf, qf[1][ks], Sacc[1][tk], 0, 0, 0);
            }
        }

        // P = exp2(S'), truncation-packed into K=32 A-fragments
        union { bf16x8 v; unsigned u[4]; } pf[2][2];
#pragma unroll
        for (int qg = 0; qg < 2; ++qg)
#pragma unroll
            for (int tk = 0; tk < 4; ++tk) {
                const float p0 = EXP2(Sacc[qg][tk][0]);
                const float p1 = EXP2(Sacc[qg][tk][1]);
                const float p2 = EXP2(Sacc[qg][tk][2]);
                const float p3 = EXP2(Sacc[qg][tk][3]);
                const int g = tk >> 1, hf = (tk & 1) * 2;
                pf[qg][g].u[hf + 0] = packtrunc(p0, p1);
                pf[qg][g].u[hf + 1] = packtrunc(p2, p3);
            }

        // Z += P * t_v (full-rate K=32), L += P * ones
#pragma unroll
        for (int g = 0; g < 2; ++g) {
#pragma unroll
            for (int tn = 0; tn < 4; ++tn) {
                const bf16x8 vf = *(const bf16x8*)&Vs[tn * 16 + l15][g * 32 + quad * 8];
                o_acc[0][tn] = __builtin_amdgcn_mfma_f32_16x16x32_bf16(pf[0][g].v, vf, o_acc[0][tn], 0, 0, 0);
                o_acc[1][tn] = __builtin_amdgcn_mfma_f32_16x16x32_bf16(pf[1][g].v, vf, o_acc[1][tn], 0, 0, 0);
            }
            Lacc[0] = __builtin_amdgcn_mfma_f32_16x16x32_bf16(pf[0][g].v, vone, Lacc[0], 0, 0, 0);
            Lacc[1] = __builtin_amdgcn_mfma_f32_16x16x32_bf16(pf[1][g].v, vone, Lacc[1], 0, 0, 0);
        }
    }

    // epilogue: Z[token][h*64 + r'], r' = tn*16+l15; L at lane quad*16, reg r
#pragma unroll
    for (int qg = 0; qg < 2; ++qg) {
#pragma unroll
        for (int r = 0; r < 4; ++r) {
            const float Lv = __shfl(Lacc[qg][r], quad << 4, 64);
            const float inv = 1.0f / Lv;
            const int token = qt * 128 + wv * 32 + qg * 16 + quad * 4 + r;
#pragma unroll
            for (int tn = 0; tn < 4; ++tn) {
                const int col = h * 64 + tn * 16 + l15;
                Z[(size_t)(b * 1024 + token) * 768 + col] = f2b(o_acc[qg][tn][r] * inv);
            }
        }
    }
}

// ---------------------------------------------------------------------------
// Kernel 5: out = Zcat @ Dcat^T + bias, fp32 out. 128x64 tiles, grid (12,64).
// ---------------------------------------------------------------------------
__global__ __launch_bounds__(256, 3) void gemm_out(
    const u16* __restrict__ A, const u16* __restrict__ Bt,
    float* __restrict__ C, const float* __restrict__ bias)
{
    __shared__ u16 As[128 * 32];
    __shared__ u16 Bs[64 * 32];

    const int tid  = threadIdx.x;
    const int lane = tid & 63, wv = tid >> 6;
    const int l15  = lane & 15, quad = lane >> 4;
    const int rowBase = blockIdx.y * 128;
    const int colBase = blockIdx.x * 64;

    const int srowA = wv * 32 + (lane >> 2);
    const int srowB = wv * 16 + (lane >> 2);
    const int scol  = (lane & 3) * 8;
    const u16* aSrc = A  + (size_t)(rowBase + srowA) * 768 + scol;
    const u16* bSrc = Bt + (size_t)(colBase + srowB) * 768 + scol;
    u16* aDst = As + wv * 1024;
    u16* bDst = Bs + wv * 512;

    const f32x4 zero4 = {0.f, 0.f, 0.f, 0.f};
    f32x4 acc[2][4];
#pragma unroll
    for (int tm = 0; tm < 2; ++tm)
#pragma unroll
        for (int tn = 0; tn < 4; ++tn) acc[tm][tn] = zero4;

    for (int kk = 0; kk < 768; kk += 32) {
        __syncthreads();
        g2l16(aSrc + kk,            aDst);
        g2l16(aSrc + kk + 16 * 768, aDst + 512);
        g2l16(bSrc + kk,            bDst);
        __syncthreads();

        bf16x8 af[2], bfm[4];
#pragma unroll
        for (int t = 0; t < 2; ++t)
            af[t]  = *(const bf16x8*)(As + (wv * 32 + t * 16 + l15) * 32 + quad * 8);
#pragma unroll
        for (int t = 0; t < 4; ++t)
            bfm[t] = *(const bf16x8*)(Bs + (t * 16 + l15) * 32 + quad * 8);
#pragma unroll
        for (int tm = 0; tm < 2; ++tm)
#pragma unroll
            for (int tn = 0; tn < 4; ++tn)
                acc[tm][tn] = __builtin_amdgcn_mfma_f32_16x16x32_bf16(
                    af[tm], bfm[tn], acc[tm][tn], 0, 0, 0);
    }

#pragma unroll
    for (int tm = 0; tm < 2; ++tm) {
        const int grow = rowBase + wv * 32 + tm * 16 + quad * 4;
#pragma unroll
        for (int tn = 0; tn < 4; ++tn) {
            const int gcol = colBase + tn * 16 + l15;
            const float bv = bias[gcol];
#pragma unroll
            for (int r = 0; r < 4; ++r)
                C[(size_t)(grow + r) * 768 + gcol] = acc[tm][tn][r] + bv;
        }
    }
}

// ---------------------------------------------------------------------------
extern "C" void kernel_launch(void* const* d_in, const int* in_sizes, int n_in,
                              void* d_out, int out_size, void* d_ws, size_t ws_size,
                              hipStream_t stream)
{
    const float* x      = (const float*)d_in[0];
    const float* Wq0    = (const float*)d_in[1];
    const float* Wq1    = (const float*)d_in[2];
    const float* Wq2    = (const float*)d_in[3];
    const float* Wk0    = (const float*)d_in[4];
    const float* Wk1    = (const float*)d_in[5];
    const float* Wk2    = (const float*)d_in[6];
    const float* Wv0    = (const float*)d_in[7];
    const float* Wv1    = (const float*)d_in[8];
    const float* Wv2    = (const float*)d_in[9];
    const float* proj_w = (const float*)d_in[10];
    const float* proj_b = (const float*)d_in[11];
    float* outp = (float*)d_out;

    char* ws = (char*)d_ws;
    u16* T    = (u16*)ws;                       // 8192*128*2 = 2,097,152 B
    u16* tvt  = (u16*)(ws + 2097152);           // 64*8192*2  = 1,048,576 B
    u16* G    = (u16*)(ws + 3145728);           //   294,912 B
    u16* Mqkb = (u16*)(ws + 3440640);           //    98,304 B
    u16* Dcat = (u16*)(ws + 3538944);           // 1,179,648 B
    u16* Zcat = (u16*)(ws + 4718592);           // 12,582,912 B
    u16* kp   = (u16*)(ws + 17301504);          // 12,582,912 B; end = 29,884,416 B

    build_prep<<<876, 256, 0, stream>>>(Wq0, Wq1, Wq2, Wk0, Wk1, Wk2, Wv0, Wv1, Wv2,
                                        proj_w, G, Mqkb, Dcat);
    gemm_t<<<dim3(3, 128), 256, 0, stream>>>(x, G, T, tvt);
    gemm_expand<<<dim3(6, 64), 256, 0, stream>>>(T, Mqkb, kp);
    flash_attn7<<<dim3(96, 8), 256, 0, stream>>>(T, kp, tvt, Zcat);
    gemm_out<<<dim3(12, 64), 256, 0, stream>>>(Zcat, Dcat, outp, proj_b);
}

// Round 9
// 175.913 us; speedup vs baseline: 1.0348x; 1.0348x over previous
//
#include <hip/hip_runtime.h>

typedef unsigned short u16;
typedef __attribute__((ext_vector_type(8))) short bf16x8;
typedef __attribute__((ext_vector_type(4))) float f32x4;
typedef __attribute__((ext_vector_type(4))) unsigned short u16x4;
typedef __attribute__((ext_vector_type(8))) unsigned short u16x8;

#define AS1 __attribute__((address_space(1)))
#define AS3 __attribute__((address_space(3)))

__device__ __forceinline__ float b2f(u16 s) {
    return __uint_as_float(((unsigned)s) << 16);
}
__device__ __forceinline__ u16 f2b(float f) {
    unsigned u = __float_as_uint(f);
    unsigned r = 0x7fffu + ((u >> 16) & 1u);
    return (u16)((u + r) >> 16);
}

// pack hi16(p1):hi16(p0) in one v_perm_b32 (truncating bf16 convert x2)
__device__ __forceinline__ unsigned packtrunc(float p0, float p1) {
#if __has_builtin(__builtin_amdgcn_perm)
    return __builtin_amdgcn_perm(__float_as_uint(p1), __float_as_uint(p0), 0x07060302u);
#else
    return (__float_as_uint(p0) >> 16) | (__float_as_uint(p1) & 0xffff0000u);
#endif
}

// async global->LDS, 16B per lane
__device__ __forceinline__ void g2l16(const u16* g, u16* l) {
    __builtin_amdgcn_global_load_lds((const AS1 void*)g, (AS3 void*)l, 16, 0, 0);
}

#if __has_builtin(__builtin_amdgcn_exp2f)
#define EXP2(x) __builtin_amdgcn_exp2f(x)
#else
#define EXP2(x) exp2f(x)
#endif

// ---------------------------------------------------------------------------
// Kernel 1: weight prep. Sections by blockIdx:
//  bx <  576 : G[which*64+r][h*64+d] = W1[h,r]*W2[d,r]           (192 x 768)
//  576..623  : Mqk[h*64+r1][r2] = qs * sum_d W0q[h*64+d,r1]*W0k[h*64+d,r2]
//              (48 blocks: 4 per head, 1024 outputs each)
//  bx >= 624 : Dcat[m][h*64+r] = sum_d PW[m,h*64+d]*Wv0[h*64+d,r] (proj+W0v)
// ---------------------------------------------------------------------------
__global__ __launch_bounds__(256) void build_prep(
    const float* __restrict__ Wq0, const float* __restrict__ Wq1, const float* __restrict__ Wq2,
    const float* __restrict__ Wk0, const float* __restrict__ Wk1, const float* __restrict__ Wk2,
    const float* __restrict__ Wv0, const float* __restrict__ Wv1, const float* __restrict__ Wv2,
    const float* __restrict__ PW,
    u16* __restrict__ G, u16* __restrict__ Mqkb, u16* __restrict__ Dcat)
{
    const int bx = blockIdx.x;
    const int t = threadIdx.x;
    if (bx < 576) {
        const int idx = bx * 256 + t;           // < 147456
        const int row = idx / 768, c = idx - row * 768;
        const int which = row >> 6, r = row & 63;
        const int h = c >> 6, d = c & 63;
        const float* W1 = (which == 0) ? Wq1 : (which == 1) ? Wk1 : Wv1;
        const float* W2 = (which == 0) ? Wq2 : (which == 1) ? Wk2 : Wv2;
        G[idx] = f2b(W1[h * 64 + r] * W2[d * 64 + r]);
    } else if (bx < 624) {
        __shared__ float wq[64 * 65];
        __shared__ float wk[64 * 65];
        const int hq = bx - 576;                // 0..47
        const int h = hq >> 2, quarter = hq & 3;
        const float qs = 0.125f * 1.4426950408889634f;
        for (int i = t; i < 4096; i += 256) {
            const int dd = i >> 6, r = i & 63;
            wq[dd * 65 + r] = Wq0[(h * 64 + dd) * 64 + r] * qs;
            wk[dd * 65 + r] = Wk0[(h * 64 + dd) * 64 + r];
        }
        __syncthreads();
        const int j0 = quarter * 1024 + t * 4;
        const int r1 = j0 >> 6, r2b = j0 & 63;
        u16x4 pk;
#pragma unroll
        for (int jj = 0; jj < 4; ++jj) {
            float acc = 0.f;
#pragma unroll
            for (int dd = 0; dd < 64; ++dd)
                acc += wq[dd * 65 + r1] * wk[dd * 65 + r2b + jj];
            ((u16*)&pk)[jj] = f2b(acc);
        }
        *(u16x4*)(Mqkb + (size_t)(h * 64 + r1) * 64 + r2b) = pk;
    } else {
        __shared__ float w0s[64 * 65];   // w0s[d][r] = Wv0[h*64+d][r]
        __shared__ float pws[32 * 65];   // pws[mi][d] = PW[mBase+mi][h*64+d]
        const int hb = bx - 624;         // 0..287
        const int h = hb / 24, mBase = (hb - h * 24) * 32;
        for (int i = t; i < 4096; i += 256) {
            const int d = i >> 6, r = i & 63;
            w0s[d * 65 + r] = Wv0[(h * 64 + d) * 64 + r];
        }
        for (int i = t; i < 2048; i += 256) {
            const int mi = i >> 6, d = i & 63;
            pws[mi * 65 + d] = PW[(size_t)(mBase + mi) * 768 + h * 64 + d];
        }
        __syncthreads();
        const int r = t & 63, mi0 = t >> 6;
        float w0c[64];
#pragma unroll
        for (int d = 0; d < 64; ++d) w0c[d] = w0s[d * 65 + r];
        for (int mi = mi0; mi < 32; mi += 4) {
            float acc = 0.f;
#pragma unroll
            for (int d = 0; d < 64; ++d) acc += pws[mi * 65 + d] * w0c[d];
            Dcat[(size_t)(mBase + mi) * 768 + h * 64 + r] = f2b(acc);
        }
    }
}

// ---------------------------------------------------------------------------
// Kernel 2: t = x(fp32) @ G^T-layout (M=8192, K=768). Grid (3,128), 64x64 tile.
// XCD-aware remap: the 3 col-tiles of one token-row land on the SAME XCD in
// adjacent dispatch rounds -> x row (196KB) is fetched from HBM once, re-read
// from that XCD's L2. Col-tiles 0,1 -> T[8192][128]; tile 2 -> tvt[64][8192].
// ---------------------------------------------------------------------------
__global__ __launch_bounds__(256, 2) void gemm_t(
    const float* __restrict__ X, const u16* __restrict__ G,
    u16* __restrict__ T, u16* __restrict__ tvt)
{
    __shared__ u16 As[64 * 32];
    __shared__ u16 Bs[64 * 32];

    const int tid = threadIdx.x;
    const int lane = tid & 63, wv = tid >> 6;
    const int l15 = lane & 15, quad = lane >> 4;

    // remap: lin -> (row, col) with same-row col-tiles on one XCD
    const int lin = blockIdx.x + 3 * blockIdx.y;   // 0..383
    const int xcd = lin & 7, j = lin >> 3;         // j 0..47
    const int col = j % 3, rowhi = j / 3;          // rowhi 0..15
    const int rowBase = (rowhi * 8 + xcd) * 64;
    const int colBase = col * 64;

    const int srow = tid >> 2;          // 0..63
    const int scol = (tid & 3) * 8;     // 0/8/16/24
    const float* aS = X + (size_t)(rowBase + srow) * 768 + scol;
    const u16*  bS  = G + (size_t)(colBase + srow) * 768 + scol;

    float4 a0 = *(const float4*)(aS);
    float4 a1 = *(const float4*)(aS + 4);
    int4   b0 = *(const int4*)(bS);

    const f32x4 zero4 = {0.f, 0.f, 0.f, 0.f};
    f32x4 acc[4];
#pragma unroll
    for (int tn = 0; tn < 4; ++tn) acc[tn] = zero4;

    for (int kk = 0; kk < 768; kk += 32) {
        __syncthreads();
        u16x8 ap;
        ap[0] = f2b(a0.x); ap[1] = f2b(a0.y); ap[2] = f2b(a0.z); ap[3] = f2b(a0.w);
        ap[4] = f2b(a1.x); ap[5] = f2b(a1.y); ap[6] = f2b(a1.z); ap[7] = f2b(a1.w);
        *(u16x8*)&As[srow * 32 + scol] = ap;
        *(int4*)&Bs[srow * 32 + scol]  = b0;
        __syncthreads();

        if (kk < 736) {
            a0 = *(const float4*)(aS + kk + 32);
            a1 = *(const float4*)(aS + kk + 36);
            b0 = *(const int4*)(bS + kk + 32);
        }

        const bf16x8 af = *(const bf16x8*)(As + (wv * 16 + l15) * 32 + quad * 8);
#pragma unroll
        for (int tn = 0; tn < 4; ++tn) {
            const bf16x8 bf = *(const bf16x8*)(Bs + (tn * 16 + l15) * 32 + quad * 8);
            acc[tn] = __builtin_amdgcn_mfma_f32_16x16x32_bf16(af, bf, acc[tn], 0, 0, 0);
        }
    }

    if (colBase < 128) {
#pragma unroll
        for (int tn = 0; tn < 4; ++tn) {
            const int c = colBase + tn * 16 + l15;
#pragma unroll
            for (int r = 0; r < 4; ++r) {
                const int grow = rowBase + wv * 16 + quad * 4 + r;
                T[(size_t)grow * 128 + c] = f2b(acc[tn][r]);
            }
        }
    } else {
        // v-part: write transposed tvt[r'][token], 4 tokens packed per store
#pragma unroll
        for (int tn = 0; tn < 4; ++tn) {
            const int rr = tn * 16 + l15;                    // r index 0..63
            const int grow = rowBase + wv * 16 + quad * 4;   // token base
            u16x4 pk;
            pk.x = f2b(acc[tn][0]); pk.y = f2b(acc[tn][1]);
            pk.z = f2b(acc[tn][2]); pk.w = f2b(acc[tn][3]);
            *(u16x4*)(tvt + (size_t)rr * 8192 + grow) = pk;
        }
    }
}

// ---------------------------------------------------------------------------
// Kernel 3: k' = Mqk @ t_k^T  (K=64, operands swapped so the 4 accumulator
// regs span 4 consecutive r1 -> packed u16x4 stores). Grid (6 m-tiles, 64 n).
// Output layout [bh][l][r1] (unchanged for flash).
// ---------------------------------------------------------------------------
__global__ __launch_bounds__(256, 2) void gemm_expand(
    const u16* __restrict__ T, const u16* __restrict__ Mqkb, u16* __restrict__ kp)
{
    __shared__ u16 As[128 * 32];
    __shared__ u16 Bs[128 * 32];

    const int tid  = threadIdx.x;
    const int lane = tid & 63, wv = tid >> 6;
    const int l15  = lane & 15, quad = lane >> 4;
    const int rowBase = blockIdx.x * 128;    // hr1 dim (768)
    const int colBase = blockIdx.y * 128;    // token dim (8192)

    const int srow = wv * 32 + (lane >> 2);
    const int scol = (lane & 3) * 8;
    const u16* aSrc = Mqkb + (size_t)(rowBase + srow) * 64 + scol;
    const u16* bSrc = T    + (size_t)(colBase + srow) * 128 + 64 + scol;   // t_k part
    u16* aDst = As + wv * 1024;
    u16* bDst = Bs + wv * 1024;

    const f32x4 zero4 = {0.f, 0.f, 0.f, 0.f};
    f32x4 acc[4][4];
#pragma unroll
    for (int tm = 0; tm < 4; ++tm)
#pragma unroll
        for (int tn = 0; tn < 4; ++tn) acc[tm][tn] = zero4;

    const int wr = (wv >> 1) * 64, wc = (wv & 1) * 64;

    for (int kk = 0; kk < 64; kk += 32) {
        __syncthreads();
        g2l16(aSrc + kk,            aDst);
        g2l16(aSrc + kk + 16 * 64,  aDst + 512);
        g2l16(bSrc + kk,            bDst);
        g2l16(bSrc + kk + 16 * 128, bDst + 512);
        __syncthreads();

        bf16x8 af[4], bfm[4];
#pragma unroll
        for (int t = 0; t < 4; ++t) {
            af[t]  = *(const bf16x8*)(As + (wr + t * 16 + l15) * 32 + quad * 8);
            bfm[t] = *(const bf16x8*)(Bs + (wc + t * 16 + l15) * 32 + quad * 8);
        }
#pragma unroll
        for (int tm = 0; tm < 4; ++tm)
#pragma unroll
            for (int tn = 0; tn < 4; ++tn)
                acc[tm][tn] = __builtin_amdgcn_mfma_f32_16x16x32_bf16(
                    af[tm], bfm[tn], acc[tm][tn], 0, 0, 0);
    }

    // epilogue: rows = hr1 (4 consecutive in regs), cols = token
#pragma unroll
    for (int tm = 0; tm < 4; ++tm) {
        const int hr1 = rowBase + wr + tm * 16 + quad * 4;
        const int h = hr1 >> 6, r1 = hr1 & 63;
#pragma unroll
        for (int tn = 0; tn < 4; ++tn) {
            const int token = colBase + wc + tn * 16 + l15;
            const int b = token >> 10, l = token & 1023;
            u16x4 pk;
            pk.x = f2b(acc[tm][tn][0]); pk.y = f2b(acc[tm][tn][1]);
            pk.z = f2b(acc[tm][tn][2]); pk.w = f2b(acc[tm][tn][3]);
            *(u16x4*)(kp + (((size_t)(b * 12 + h) * 1024 + l) << 6) + r1) = pk;
        }
    }
}

// ---------------------------------------------------------------------------
// Kernel 4: flash attention v7, fully in t-space. Grid (96,8): x=bh, y=qt —
// all 8 q-tiles of one bh land on the SAME XCD (96 % 8 == 0).
// ---------------------------------------------------------------------------
__global__ __launch_bounds__(256, 3) void flash_attn7(
    const u16* __restrict__ T, const u16* __restrict__ kprime,
    const u16* __restrict__ tvt, u16* __restrict__ Z)
{
    const int bh = blockIdx.x;          // 0..95
    const int qt = blockIdx.y;          // 0..7 (128 q rows each)
    const int b = bh / 12, h = bh - b * 12;
    const u16* qp = T + ((size_t)b * 1024 + qt * 128) * 128;   // t_q rows, stride 128
    const u16* kp = kprime + (size_t)bh * 65536;
    const u16* vp = tvt + b * 1024;     // tvt[r][8192], slice cols b*1024..

    __shared__ u16 Ks[64][72];
    __shared__ u16 Vs[64][72];          // Vs[r][key]

    const int t = threadIdx.x;
    const int lane = t & 63, wv = t >> 6;
    const int l15 = lane & 15, quad = lane >> 4;

    bf16x8 qf[2][2];
#pragma unroll
    for (int qg = 0; qg < 2; ++qg) {
        const u16* qrow = qp + (size_t)(wv * 32 + qg * 16 + l15) * 128;
        qf[qg][0] = *(const bf16x8*)(qrow + quad * 8);
        qf[qg][1] = *(const bf16x8*)(qrow + 32 + quad * 8);
    }

    const int srow = t >> 2;            // key-row / r-row 0..63
    const int scol = (t & 3) * 16;
    const int p5 = srow & 31;
    const int lrow = (srow & 32) | ((p5 & 4) << 2) | ((p5 & 16) >> 1)
                   | ((p5 & 8) >> 1) | (p5 & 3);   // permuted K row

    bf16x8 vone = {};
    if (l15 == 0) {
#pragma unroll
        for (int j = 0; j < 8; ++j) vone[j] = (short)0x3F80;
    }

    int4 kr0 = *(const int4*)(kp + srow * 64 + scol);
    int4 kr1 = *(const int4*)(kp + srow * 64 + scol + 8);
    int4 vr0 = *(const int4*)(vp + (size_t)srow * 8192 + scol);
    int4 vr1 = *(const int4*)(vp + (size_t)srow * 8192 + scol + 8);

    const f32x4 zero4 = {0.f, 0.f, 0.f, 0.f};
    f32x4 o_acc[2][4];
    f32x4 Lacc[2] = {zero4, zero4};
#pragma unroll
    for (int qg = 0; qg < 2; ++qg)
#pragma unroll
        for (int tn = 0; tn < 4; ++tn) o_acc[qg][tn] = zero4;

    for (int kt = 0; kt < 16; ++kt) {
        __syncthreads();
        *(int4*)&Ks[lrow][scol]     = kr0;
        *(int4*)&Ks[lrow][scol + 8] = kr1;
        *(int4*)&Vs[srow][scol]     = vr0;
        *(int4*)&Vs[srow][scol + 8] = vr1;
        __syncthreads();

        if (kt < 15) {
            kr0 = *(const int4*)(kp + (kt + 1) * 4096 + srow * 64 + scol);
            kr1 = *(const int4*)(kp + (kt + 1) * 4096 + srow * 64 + scol + 8);
            vr0 = *(const int4*)(vp + (size_t)srow * 8192 + (kt + 1) * 64 + scol);
            vr1 = *(const int4*)(vp + (size_t)srow * 8192 + (kt + 1) * 64 + scol + 8);
        }

        // S^T = K' x t_q^T (keys permuted per tile)
        f32x4 Sacc[2][4];
#pragma unroll
        for (int qg = 0; qg < 2; ++qg)
#pragma unroll
            for (int tk = 0; tk < 4; ++tk) Sacc[qg][tk] = zero4;
#pragma unroll
        for (int ks = 0; ks < 2; ++ks) {
#pragma unroll
            for (int tk = 0; tk < 4; ++tk) {
                const bf16x8 kf = *(const bf16x8*)&Ks[tk * 16 + l15][ks * 32 + quad * 8];
                Sacc[0][tk] = __builtin_amdgcn_mfma_f32_16x16x32_bf16(kf, qf[0][ks], Sacc[0][tk], 0, 0, 0);
                Sacc[1][tk] = __builtin_amdgcn_mfma_f32_16x16x32_bf16(kf, qf[1][ks], Sacc[1][tk], 0, 0, 0);
            }
        }

        // P = exp2(S'), truncation-packed into K=32 A-fragments
        union { bf16x8 v; unsigned u[4]; } pf[2][2];
#pragma unroll
        for (int qg = 0; qg < 2; ++qg)
#pragma unroll
            for (int tk = 0; tk < 4; ++tk) {
                const float p0 = EXP2(Sacc[qg][tk][0]);
                const float p1 = EXP2(Sacc[qg][tk][1]);
                const float p2 = EXP2(Sacc[qg][tk][2]);
                const float p3 = EXP2(Sacc[qg][tk][3]);
                const int g = tk >> 1, hf = (tk & 1) * 2;
                pf[qg][g].u[hf + 0] = packtrunc(p0, p1);
                pf[qg][g].u[hf + 1] = packtrunc(p2, p3);
            }

        // Z += P * t_v (full-rate K=32), L += P * ones
#pragma unroll
        for (int g = 0; g < 2; ++g) {
#pragma unroll
            for (int tn = 0; tn < 4; ++tn) {
                const bf16x8 vf = *(const bf16x8*)&Vs[tn * 16 + l15][g * 32 + quad * 8];
                o_acc[0][tn] = __builtin_amdgcn_mfma_f32_16x16x32_bf16(pf[0][g].v, vf, o_acc[0][tn], 0, 0, 0);
                o_acc[1][tn] = __builtin_amdgcn_mfma_f32_16x16x32_bf16(pf[1][g].v, vf, o_acc[1][tn], 0, 0, 0);
            }
            Lacc[0] = __builtin_amdgcn_mfma_f32_16x16x32_bf16(pf[0][g].v, vone, Lacc[0], 0, 0, 0);
            Lacc[1] = __builtin_amdgcn_mfma_f32_16x16x32_bf16(pf[1][g].v, vone, Lacc[1], 0, 0, 0);
        }
    }

    // epilogue: Z[token][h*64 + r'], r' = tn*16+l15; L at lane quad*16, reg r
#pragma unroll
    for (int qg = 0; qg < 2; ++qg) {
#pragma unroll
        for (int r = 0; r < 4; ++r) {
            const float Lv = __shfl(Lacc[qg][r], quad << 4, 64);
            const float inv = 1.0f / Lv;
            const int token = qt * 128 + wv * 32 + qg * 16 + quad * 4 + r;
#pragma unroll
            for (int tn = 0; tn < 4; ++tn) {
                const int col = h * 64 + tn * 16 + l15;
                Z[(size_t)(b * 1024 + token) * 768 + col] = f2b(o_acc[qg][tn][r] * inv);
            }
        }
    }
}

// ---------------------------------------------------------------------------
// Kernel 5: out = Zcat @ Dcat^T + bias, fp32 out. 128x64 tiles, grid (12,64).
// XCD-aware remap: the 12 col-blocks of one Zcat row-tile share an XCD so the
// A re-reads hit L2 (per-XCD working set ~2.8 MB < 4 MB).
// ---------------------------------------------------------------------------
__global__ __launch_bounds__(256, 3) void gemm_out(
    const u16* __restrict__ A, const u16* __restrict__ Bt,
    float* __restrict__ C, const float* __restrict__ bias)
{
    __shared__ u16 As[128 * 32];
    __shared__ u16 Bs[64 * 32];

    const int tid  = threadIdx.x;
    const int lane = tid & 63, wv = tid >> 6;
    const int l15  = lane & 15, quad = lane >> 4;

    const int lin = blockIdx.x + 12 * blockIdx.y;  // 0..767
    const int xcd = lin & 7, j = lin >> 3;         // j 0..95
    const int colT = j % 12, rowhi = j / 12;       // rowhi 0..7
    const int rowBase = (rowhi * 8 + xcd) * 128;
    const int colBase = colT * 64;

    const int srowA = wv * 32 + (lane >> 2);
    const int srowB = wv * 16 + (lane >> 2);
    const int scol  = (lane & 3) * 8;
    const u16* aSrc = A  + (size_t)(rowBase + srowA) * 768 + scol;
    const u16* bSrc = Bt + (size_t)(colBase + srowB) * 768 + scol;
    u16* aDst = As + wv * 1024;
    u16* bDst = Bs + wv * 512;

    const f32x4 zero4 = {0.f, 0.f, 0.f, 0.f};
    f32x4 acc[2][4];
#pragma unroll
    for (int tm = 0; tm < 2; ++tm)
#pragma unroll
        for (int tn = 0; tn < 4; ++tn) acc[tm][tn] = zero4;

    for (int kk = 0; kk < 768; kk += 32) {
        __syncthreads();
        g2l16(aSrc + kk,            aDst);
        g2l16(aSrc + kk + 16 * 768, aDst + 512);
        g2l16(bSrc + kk,            bDst);
        __syncthreads();

        bf16x8 af[2], bfm[4];
#pragma unroll
        for (int t = 0; t < 2; ++t)
            af[t]  = *(const bf16x8*)(As + (wv * 32 + t * 16 + l15) * 32 + quad * 8);
#pragma unroll
        for (int t = 0; t < 4; ++t)
            bfm[t] = *(const bf16x8*)(Bs + (t * 16 + l15) * 32 + quad * 8);
#pragma unroll
        for (int tm = 0; tm < 2; ++tm)
#pragma unroll
            for (int tn = 0; tn < 4; ++tn)
                acc[tm][tn] = __builtin_amdgcn_mfma_f32_16x16x32_bf16(
                    af[tm], bfm[tn], acc[tm][tn], 0, 0, 0);
    }

#pragma unroll
    for (int tm = 0; tm < 2; ++tm) {
        const int grow = rowBase + wv * 32 + tm * 16 + quad * 4;
#pragma unroll
        for (int tn = 0; tn < 4; ++tn) {
            const int gcol = colBase + tn * 16 + l15;
            const float bv = bias[gcol];
#pragma unroll
            for (int r = 0; r < 4; ++r)
                C[(size_t)(grow + r) * 768 + gcol] = acc[tm][tn][r] + bv;
        }
    }
}

// ---------------------------------------------------------------------------
extern "C" void kernel_launch(void* const* d_in, const int* in_sizes, int n_in,
                              void* d_out, int out_size, void* d_ws, size_t ws_size,
                              hipStream_t stream)
{
    const float* x      = (const float*)d_in[0];
    const float* Wq0    = (const float*)d_in[1];
    const float* Wq1    = (const float*)d_in[2];
    const float* Wq2    = (const float*)d_in[3];
    const float* Wk0    = (const float*)d_in[4];
    const float* Wk1    = (const float*)d_in[5];
    const float* Wk2    = (const float*)d_in[6];
    const float* Wv0    = (const float*)d_in[7];
    const float* Wv1    = (const float*)d_in[8];
    const float* Wv2    = (const float*)d_in[9];
    const float* proj_w = (const float*)d_in[10];
    const float* proj_b = (const float*)d_in[11];
    float* outp = (float*)d_out;

    char* ws = (char*)d_ws;
    u16* T    = (u16*)ws;                       // 8192*128*2 = 2,097,152 B
    u16* tvt  = (u16*)(ws + 2097152);           // 64*8192*2  = 1,048,576 B
    u16* G    = (u16*)(ws + 3145728);           //   294,912 B
    u16* Mqkb = (u16*)(ws + 3440640);           //    98,304 B
    u16* Dcat = (u16*)(ws + 3538944);           // 1,179,648 B
    u16* Zcat = (u16*)(ws + 4718592);           // 12,582,912 B
    u16* kp   = (u16*)(ws + 17301504);          // 12,582,912 B; end = 29,884,416 B

    build_prep<<<912, 256, 0, stream>>>(Wq0, Wq1, Wq2, Wk0, Wk1, Wk2, Wv0, Wv1, Wv2,
                                        proj_w, G, Mqkb, Dcat);
    gemm_t<<<dim3(3, 128), 256, 0, stream>>>(x, G, T, tvt);
    gemm_expand<<<dim3(6, 64), 256, 0, stream>>>(T, Mqkb, kp);
    flash_attn7<<<dim3(96, 8), 256, 0, stream>>>(T, kp, tvt, Zcat);
    gemm_out<<<dim3(12, 64), 256, 0, stream>>>(Zcat, Dcat, outp, proj_b);
}

// Round 10
// 173.743 us; speedup vs baseline: 1.0477x; 1.0125x over previous
//
#include <hip/hip_runtime.h>

typedef unsigned short u16;
typedef __attribute__((ext_vector_type(8))) short bf16x8;
typedef __attribute__((ext_vector_type(4))) float f32x4;
typedef __attribute__((ext_vector_type(4))) unsigned short u16x4;
typedef __attribute__((ext_vector_type(8))) unsigned short u16x8;

#define AS1 __attribute__((address_space(1)))
#define AS3 __attribute__((address_space(3)))

__device__ __forceinline__ float b2f(u16 s) {
    return __uint_as_float(((unsigned)s) << 16);
}
__device__ __forceinline__ u16 f2b(float f) {
    unsigned u = __float_as_uint(f);
    unsigned r = 0x7fffu + ((u >> 16) & 1u);
    return (u16)((u + r) >> 16);
}

// pack hi16(p1):hi16(p0) in one v_perm_b32 (truncating bf16 convert x2)
__device__ __forceinline__ unsigned packtrunc(float p0, float p1) {
#if __has_builtin(__builtin_amdgcn_perm)
    return __builtin_amdgcn_perm(__float_as_uint(p1), __float_as_uint(p0), 0x07060302u);
#else
    return (__float_as_uint(p0) >> 16) | (__float_as_uint(p1) & 0xffff0000u);
#endif
}

// async global->LDS, 16B per lane
__device__ __forceinline__ void g2l16(const u16* g, u16* l) {
    __builtin_amdgcn_global_load_lds((const AS1 void*)g, (AS3 void*)l, 16, 0, 0);
}

#if __has_builtin(__builtin_amdgcn_exp2f)
#define EXP2(x) __builtin_amdgcn_exp2f(x)
#else
#define EXP2(x) exp2f(x)
#endif

// ---------------------------------------------------------------------------
// Kernel 1: weight prep. Sections by blockIdx:
//  bx <  576 : G[which*64+r][h*64+d] = W1[h,r]*W2[d,r]           (192 x 768)
//  576..623  : MqkT[h*64+r2][r1] = qs * sum_d W0q[h*64+d,r1]*W0k[h*64+d,r2]
//              (TRANSPOSED Mqk so flash can load B-fragments directly)
//  bx >= 624 : Dcat[m][h*64+r] = sum_d PW[m,h*64+d]*Wv0[h*64+d,r] (proj+W0v)
// ---------------------------------------------------------------------------
__global__ __launch_bounds__(256) void build_prep(
    const float* __restrict__ Wq0, const float* __restrict__ Wq1, const float* __restrict__ Wq2,
    const float* __restrict__ Wk0, const float* __restrict__ Wk1, const float* __restrict__ Wk2,
    const float* __restrict__ Wv0, const float* __restrict__ Wv1, const float* __restrict__ Wv2,
    const float* __restrict__ PW,
    u16* __restrict__ G, u16* __restrict__ MqkT, u16* __restrict__ Dcat)
{
    const int bx = blockIdx.x;
    const int t = threadIdx.x;
    if (bx < 576) {
        const int idx = bx * 256 + t;           // < 147456
        const int row = idx / 768, c = idx - row * 768;
        const int which = row >> 6, r = row & 63;
        const int h = c >> 6, d = c & 63;
        const float* W1 = (which == 0) ? Wq1 : (which == 1) ? Wk1 : Wv1;
        const float* W2 = (which == 0) ? Wq2 : (which == 1) ? Wk2 : Wv2;
        G[idx] = f2b(W1[h * 64 + r] * W2[d * 64 + r]);
    } else if (bx < 624) {
        __shared__ float wq[64 * 65];
        __shared__ float wk[64 * 65];
        const int hq = bx - 576;                // 0..47
        const int h = hq >> 2, quarter = hq & 3;
        const float qs = 0.125f * 1.4426950408889634f;
        for (int i = t; i < 4096; i += 256) {
            const int dd = i >> 6, r = i & 63;
            wq[dd * 65 + r] = Wq0[(h * 64 + dd) * 64 + r] * qs;
            wk[dd * 65 + r] = Wk0[(h * 64 + dd) * 64 + r];
        }
        __syncthreads();
        const int j0 = quarter * 1024 + t * 4;
        const int r2 = j0 >> 6, r1b = j0 & 63;   // output row = r2, packed cols = r1
        u16x4 pk;
#pragma unroll
        for (int jj = 0; jj < 4; ++jj) {
            float acc = 0.f;
#pragma unroll
            for (int dd = 0; dd < 64; ++dd)
                acc += wk[dd * 65 + r2] * wq[dd * 65 + r1b + jj];
            ((u16*)&pk)[jj] = f2b(acc);
        }
        *(u16x4*)(MqkT + (size_t)(h * 64 + r2) * 64 + r1b) = pk;
    } else {
        __shared__ float w0s[64 * 65];   // w0s[d][r] = Wv0[h*64+d][r]
        __shared__ float pws[32 * 65];   // pws[mi][d] = PW[mBase+mi][h*64+d]
        const int hb = bx - 624;         // 0..287
        const int h = hb / 24, mBase = (hb - h * 24) * 32;
        for (int i = t; i < 4096; i += 256) {
            const int d = i >> 6, r = i & 63;
            w0s[d * 65 + r] = Wv0[(h * 64 + d) * 64 + r];
        }
        for (int i = t; i < 2048; i += 256) {
            const int mi = i >> 6, d = i & 63;
            pws[mi * 65 + d] = PW[(size_t)(mBase + mi) * 768 + h * 64 + d];
        }
        __syncthreads();
        const int r = t & 63, mi0 = t >> 6;
        float w0c[64];
#pragma unroll
        for (int d = 0; d < 64; ++d) w0c[d] = w0s[d * 65 + r];
        for (int mi = mi0; mi < 32; mi += 4) {
            float acc = 0.f;
#pragma unroll
            for (int d = 0; d < 64; ++d) acc += pws[mi * 65 + d] * w0c[d];
            Dcat[(size_t)(mBase + mi) * 768 + h * 64 + r] = f2b(acc);
        }
    }
}

// ---------------------------------------------------------------------------
// Kernel 2: t = x(fp32) @ G^T-layout (M=8192, K=768). Grid (3,128), 64x64 tile.
// XCD-aware remap: the 3 col-tiles of one token-row land on the SAME XCD.
// Col-tiles 0,1 -> T[8192][128]; tile 2 -> tvt[64][8192] (transposed).
// ---------------------------------------------------------------------------
__global__ __launch_bounds__(256, 2) void gemm_t(
    const float* __restrict__ X, const u16* __restrict__ G,
    u16* __restrict__ T, u16* __restrict__ tvt)
{
    __shared__ u16 As[64 * 32];
    __shared__ u16 Bs[64 * 32];

    const int tid = threadIdx.x;
    const int lane = tid & 63, wv = tid >> 6;
    const int l15 = lane & 15, quad = lane >> 4;

    const int lin = blockIdx.x + 3 * blockIdx.y;   // 0..383
    const int xcd = lin & 7, j = lin >> 3;         // j 0..47
    const int col = j % 3, rowhi = j / 3;          // rowhi 0..15
    const int rowBase = (rowhi * 8 + xcd) * 64;
    const int colBase = col * 64;

    const int srow = tid >> 2;          // 0..63
    const int scol = (tid & 3) * 8;     // 0/8/16/24
    const float* aS = X + (size_t)(rowBase + srow) * 768 + scol;
    const u16*  bS  = G + (size_t)(colBase + srow) * 768 + scol;

    float4 a0 = *(const float4*)(aS);
    float4 a1 = *(const float4*)(aS + 4);
    int4   b0 = *(const int4*)(bS);

    const f32x4 zero4 = {0.f, 0.f, 0.f, 0.f};
    f32x4 acc[4];
#pragma unroll
    for (int tn = 0; tn < 4; ++tn) acc[tn] = zero4;

    for (int kk = 0; kk < 768; kk += 32) {
        __syncthreads();
        u16x8 ap;
        ap[0] = f2b(a0.x); ap[1] = f2b(a0.y); ap[2] = f2b(a0.z); ap[3] = f2b(a0.w);
        ap[4] = f2b(a1.x); ap[5] = f2b(a1.y); ap[6] = f2b(a1.z); ap[7] = f2b(a1.w);
        *(u16x8*)&As[srow * 32 + scol] = ap;
        *(int4*)&Bs[srow * 32 + scol]  = b0;
        __syncthreads();

        if (kk < 736) {
            a0 = *(const float4*)(aS + kk + 32);
            a1 = *(const float4*)(aS + kk + 36);
            b0 = *(const int4*)(bS + kk + 32);
        }

        const bf16x8 af = *(const bf16x8*)(As + (wv * 16 + l15) * 32 + quad * 8);
#pragma unroll
        for (int tn = 0; tn < 4; ++tn) {
            const bf16x8 bf = *(const bf16x8*)(Bs + (tn * 16 + l15) * 32 + quad * 8);
            acc[tn] = __builtin_amdgcn_mfma_f32_16x16x32_bf16(af, bf, acc[tn], 0, 0, 0);
        }
    }

    if (colBase < 128) {
#pragma unroll
        for (int tn = 0; tn < 4; ++tn) {
            const int c = colBase + tn * 16 + l15;
#pragma unroll
            for (int r = 0; r < 4; ++r) {
                const int grow = rowBase + wv * 16 + quad * 4 + r;
                T[(size_t)grow * 128 + c] = f2b(acc[tn][r]);
            }
        }
    } else {
#pragma unroll
        for (int tn = 0; tn < 4; ++tn) {
            const int rr = tn * 16 + l15;                    // r index 0..63
            const int grow = rowBase + wv * 16 + quad * 4;   // token base
            u16x4 pk;
            pk.x = f2b(acc[tn][0]); pk.y = f2b(acc[tn][1]);
            pk.z = f2b(acc[tn][2]); pk.w = f2b(acc[tn][3]);
            *(u16x4*)(tvt + (size_t)rr * 8192 + grow) = pk;
        }
    }
}

// ---------------------------------------------------------------------------
// Kernel 3: flash attention v8 — q/k expansion fused via re-association:
//   S^T = t_k x Wq^T with Wq = t_q x Mqk_h computed ONCE per block (prologue:
//   16 MFMAs using the already-loaded qf + MqkT B-frags from global, then a
//   C-layout->B-layout LDS round-trip). Per-kt loop identical to v7 but K-tile
//   staged from T's t_k columns (bit-permuted rows for the K=32 PV A-layout).
// Grid (96,8): all 8 q-tiles of one bh on the SAME XCD.
// ---------------------------------------------------------------------------
__global__ __launch_bounds__(256, 3) void flash_attn8(
    const u16* __restrict__ T, const u16* __restrict__ MqkT,
    const u16* __restrict__ tvt, u16* __restrict__ Z)
{
    const int bh = blockIdx.x;          // 0..95
    const int qt = blockIdx.y;          // 0..7 (128 q rows each)
    const int b = bh / 12, h = bh - b * 12;
    const u16* qp = T + ((size_t)b * 1024 + qt * 128) * 128;   // t_q rows (cols 0..63)
    const u16* kp = T + (size_t)b * 1024 * 128 + 64;           // t_k rows (cols 64..127)
    const u16* vp = tvt + b * 1024;     // tvt[r][8192], slice cols b*1024..

    __shared__ u16 Ks[64][72];
    __shared__ u16 Vs[64][72];          // Vs[r][key]
    __shared__ u16 Ws[128][72];         // Wq relayout buffer

    const int t = threadIdx.x;
    const int lane = t & 63, wv = t >> 6;
    const int l15 = lane & 15, quad = lane >> 4;

    // t_q A-fragments (rows = q, cols = r1)
    bf16x8 qf[2][2];
#pragma unroll
    for (int qg = 0; qg < 2; ++qg) {
        const u16* qrow = qp + (size_t)(wv * 32 + qg * 16 + l15) * 128;
        qf[qg][0] = *(const bf16x8*)(qrow + quad * 8);
        qf[qg][1] = *(const bf16x8*)(qrow + 32 + quad * 8);
    }

    const int srow = t >> 2;            // key-row / r-row 0..63
    const int scol = (t & 3) * 16;
    const int p5 = srow & 31;
    const int lrow = (srow & 32) | ((p5 & 4) << 2) | ((p5 & 16) >> 1)
                   | ((p5 & 8) >> 1) | (p5 & 3);   // permuted K row

    bf16x8 vone = {};
    if (l15 == 0) {
#pragma unroll
        for (int j = 0; j < 8; ++j) vone[j] = (short)0x3F80;
    }

    // prefetch tile 0 (t_k + v) — overlaps the Wq prologue
    int4 kr0 = *(const int4*)(kp + (size_t)srow * 128 + scol);
    int4 kr1 = *(const int4*)(kp + (size_t)srow * 128 + scol + 8);
    int4 vr0 = *(const int4*)(vp + (size_t)srow * 8192 + scol);
    int4 vr1 = *(const int4*)(vp + (size_t)srow * 8192 + scol + 8);

    // ---- Wq = t_q x Mqk_h prologue ----
    const f32x4 zero4 = {0.f, 0.f, 0.f, 0.f};
    {
        f32x4 Wt[2][4];
#pragma unroll
        for (int qg = 0; qg < 2; ++qg)
#pragma unroll
            for (int tn = 0; tn < 4; ++tn) Wt[qg][tn] = zero4;
#pragma unroll
        for (int ks = 0; ks < 2; ++ks) {
#pragma unroll
            for (int tn = 0; tn < 4; ++tn) {
                const bf16x8 mb = *(const bf16x8*)(
                    MqkT + (size_t)(h * 64 + tn * 16 + l15) * 64 + ks * 32 + quad * 8);
                Wt[0][tn] = __builtin_amdgcn_mfma_f32_16x16x32_bf16(qf[0][ks], mb, Wt[0][tn], 0, 0, 0);
                Wt[1][tn] = __builtin_amdgcn_mfma_f32_16x16x32_bf16(qf[1][ks], mb, Wt[1][tn], 0, 0, 0);
            }
        }
        // C-layout -> LDS (rows = q_local, cols = r2)
#pragma unroll
        for (int qg = 0; qg < 2; ++qg)
#pragma unroll
            for (int tn = 0; tn < 4; ++tn)
#pragma unroll
                for (int r = 0; r < 4; ++r)
                    Ws[wv * 32 + qg * 16 + quad * 4 + r][tn * 16 + l15] = f2b(Wt[qg][tn][r]);
    }
    __syncthreads();
    // B-fragments of Wq: B[n=q][k=r2]
    bf16x8 wf[2][2];
#pragma unroll
    for (int qg = 0; qg < 2; ++qg) {
        wf[qg][0] = *(const bf16x8*)&Ws[wv * 32 + qg * 16 + l15][quad * 8];
        wf[qg][1] = *(const bf16x8*)&Ws[wv * 32 + qg * 16 + l15][32 + quad * 8];
    }

    f32x4 o_acc[2][4];
    f32x4 Lacc[2] = {zero4, zero4};
#pragma unroll
    for (int qg = 0; qg < 2; ++qg)
#pragma unroll
        for (int tn = 0; tn < 4; ++tn) o_acc[qg][tn] = zero4;

    for (int kt = 0; kt < 16; ++kt) {
        __syncthreads();
        *(int4*)&Ks[lrow][scol]     = kr0;
        *(int4*)&Ks[lrow][scol + 8] = kr1;
        *(int4*)&Vs[srow][scol]     = vr0;
        *(int4*)&Vs[srow][scol + 8] = vr1;
        __syncthreads();

        if (kt < 15) {
            kr0 = *(const int4*)(kp + (size_t)((kt + 1) * 64 + srow) * 128 + scol);
            kr1 = *(const int4*)(kp + (size_t)((kt + 1) * 64 + srow) * 128 + scol + 8);
            vr0 = *(const int4*)(vp + (size_t)srow * 8192 + (kt + 1) * 64 + scol);
            vr1 = *(const int4*)(vp + (size_t)srow * 8192 + (kt + 1) * 64 + scol + 8);
        }

        // S^T = t_k x Wq^T (keys permuted per tile): A = Ks frags, B = wf
        f32x4 Sacc[2][4];
#pragma unroll
        for (int qg = 0; qg < 2; ++qg)
#pragma unroll
            for (int tk = 0; tk < 4; ++tk) Sacc[qg][tk] = zero4;
#pragma unroll
        for (int ks = 0; ks < 2; ++ks) {
#pragma unroll
            for (int tk = 0; tk < 4; ++tk) {
                const bf16x8 kf = *(const bf16x8*)&Ks[tk * 16 + l15][ks * 32 + quad * 8];
                Sacc[0][tk] = __builtin_amdgcn_mfma_f32_16x16x32_bf16(kf, wf[0][ks], Sacc[0][tk], 0, 0, 0);
                Sacc[1][tk] = __builtin_amdgcn_mfma_f32_16x16x32_bf16(kf, wf[1][ks], Sacc[1][tk], 0, 0, 0);
            }
        }

        // P = exp2(S'), truncation-packed into K=32 A-fragments
        union { bf16x8 v; unsigned u[4]; } pf[2][2];
#pragma unroll
        for (int qg = 0; qg < 2; ++qg)
#pragma unroll
            for (int tk = 0; tk < 4; ++tk) {
                const float p0 = EXP2(Sacc[qg][tk][0]);
                const float p1 = EXP2(Sacc[qg][tk][1]);
                const float p2 = EXP2(Sacc[qg][tk][2]);
                const float p3 = EXP2(Sacc[qg][tk][3]);
                const int g = tk >> 1, hf = (tk & 1) * 2;
                pf[qg][g].u[hf + 0] = packtrunc(p0, p1);
                pf[qg][g].u[hf + 1] = packtrunc(p2, p3);
            }

        // Z += P * t_v (full-rate K=32), L += P * ones
#pragma unroll
        for (int g = 0; g < 2; ++g) {
#pragma unroll
            for (int tn = 0; tn < 4; ++tn) {
                const bf16x8 vf = *(const bf16x8*)&Vs[tn * 16 + l15][g * 32 + quad * 8];
                o_acc[0][tn] = __builtin_amdgcn_mfma_f32_16x16x32_bf16(pf[0][g].v, vf, o_acc[0][tn], 0, 0, 0);
                o_acc[1][tn] = __builtin_amdgcn_mfma_f32_16x16x32_bf16(pf[1][g].v, vf, o_acc[1][tn], 0, 0, 0);
            }
            Lacc[0] = __builtin_amdgcn_mfma_f32_16x16x32_bf16(pf[0][g].v, vone, Lacc[0], 0, 0, 0);
            Lacc[1] = __builtin_amdgcn_mfma_f32_16x16x32_bf16(pf[1][g].v, vone, Lacc[1], 0, 0, 0);
        }
    }

    // epilogue: Z[token][h*64 + r'], r' = tn*16+l15; L at lane quad*16, reg r
#pragma unroll
    for (int qg = 0; qg < 2; ++qg) {
#pragma unroll
        for (int r = 0; r < 4; ++r) {
            const float Lv = __shfl(Lacc[qg][r], quad << 4, 64);
            const float inv = 1.0f / Lv;
            const int token = qt * 128 + wv * 32 + qg * 16 + quad * 4 + r;
#pragma unroll
            for (int tn = 0; tn < 4; ++tn) {
                const int col = h * 64 + tn * 16 + l15;
                Z[(size_t)(b * 1024 + token) * 768 + col] = f2b(o_acc[qg][tn][r] * inv);
            }
        }
    }
}

// ---------------------------------------------------------------------------
// Kernel 4: out = Zcat @ Dcat^T + bias, fp32 out. 128x64 tiles, XCD-remapped.
// ---------------------------------------------------------------------------
__global__ __launch_bounds__(256, 3) void gemm_out(
    const u16* __restrict__ A, const u16* __restrict__ Bt,
    float* __restrict__ C, const float* __restrict__ bias)
{
    __shared__ u16 As[128 * 32];
    __shared__ u16 Bs[64 * 32];

    const int tid  = threadIdx.x;
    const int lane = tid & 63, wv = tid >> 6;
    const int l15  = lane & 15, quad = lane >> 4;

    const int lin = blockIdx.x + 12 * blockIdx.y;  // 0..767
    const int xcd = lin & 7, j = lin >> 3;         // j 0..95
    const int colT = j % 12, rowhi = j / 12;       // rowhi 0..7
    const int rowBase = (rowhi * 8 + xcd) * 128;
    const int colBase = colT * 64;

    const int srowA = wv * 32 + (lane >> 2);
    const int srowB = wv * 16 + (lane >> 2);
    const int scol  = (lane & 3) * 8;
    const u16* aSrc = A  + (size_t)(rowBase + srowA) * 768 + scol;
    const u16* bSrc = Bt + (size_t)(colBase + srowB) * 768 + scol;
    u16* aDst = As + wv * 1024;
    u16* bDst = Bs + wv * 512;

    const f32x4 zero4 = {0.f, 0.f, 0.f, 0.f};
    f32x4 acc[2][4];
#pragma unroll
    for (int tm = 0; tm < 2; ++tm)
#pragma unroll
        for (int tn = 0; tn < 4; ++tn) acc[tm][tn] = zero4;

    for (int kk = 0; kk < 768; kk += 32) {
        __syncthreads();
        g2l16(aSrc + kk,            aDst);
        g2l16(aSrc + kk + 16 * 768, aDst + 512);
        g2l16(bSrc + kk,            bDst);
        __syncthreads();

        bf16x8 af[2], bfm[4];
#pragma unroll
        for (int t = 0; t < 2; ++t)
            af[t]  = *(const bf16x8*)(As + (wv * 32 + t * 16 + l15) * 32 + quad * 8);
#pragma unroll
        for (int t = 0; t < 4; ++t)
            bfm[t] = *(const bf16x8*)(Bs + (t * 16 + l15) * 32 + quad * 8);
#pragma unroll
        for (int tm = 0; tm < 2; ++tm)
#pragma unroll
            for (int tn = 0; tn < 4; ++tn)
                acc[tm][tn] = __builtin_amdgcn_mfma_f32_16x16x32_bf16(
                    af[tm], bfm[tn], acc[tm][tn], 0, 0, 0);
    }

#pragma unroll
    for (int tm = 0; tm < 2; ++tm) {
        const int grow = rowBase + wv * 32 + tm * 16 + quad * 4;
#pragma unroll
        for (int tn = 0; tn < 4; ++tn) {
            const int gcol = colBase + tn * 16 + l15;
            const float bv = bias[gcol];
#pragma unroll
            for (int r = 0; r < 4; ++r)
                C[(size_t)(grow + r) * 768 + gcol] = acc[tm][tn][r] + bv;
        }
    }
}

// ---------------------------------------------------------------------------
extern "C" void kernel_launch(void* const* d_in, const int* in_sizes, int n_in,
                              void* d_out, int out_size, void* d_ws, size_t ws_size,
                              hipStream_t stream)
{
    const float* x      = (const float*)d_in[0];
    const float* Wq0    = (const float*)d_in[1];
    const float* Wq1    = (const float*)d_in[2];
    const float* Wq2    = (const float*)d_in[3];
    const float* Wk0    = (const float*)d_in[4];
    const float* Wk1    = (const float*)d_in[5];
    const float* Wk2    = (const float*)d_in[6];
    const float* Wv0    = (const float*)d_in[7];
    const float* Wv1    = (const float*)d_in[8];
    const float* Wv2    = (const float*)d_in[9];
    const float* proj_w = (const float*)d_in[10];
    const float* proj_b = (const float*)d_in[11];
    float* outp = (float*)d_out;

    char* ws = (char*)d_ws;
    u16* T    = (u16*)ws;                       // 8192*128*2 = 2,097,152 B
    u16* tvt  = (u16*)(ws + 2097152);           // 64*8192*2  = 1,048,576 B
    u16* G    = (u16*)(ws + 3145728);           //   294,912 B
    u16* MqkT = (u16*)(ws + 3440640);           //    98,304 B
    u16* Dcat = (u16*)(ws + 3538944);           // 1,179,648 B
    u16* Zcat = (u16*)(ws + 4718592);           // 12,582,912 B; end = 17,301,504 B

    build_prep<<<912, 256, 0, stream>>>(Wq0, Wq1, Wq2, Wk0, Wk1, Wk2, Wv0, Wv1, Wv2,
                                        proj_w, G, MqkT, Dcat);
    gemm_t<<<dim3(3, 128), 256, 0, stream>>>(x, G, T, tvt);
    flash_attn8<<<dim3(96, 8), 256, 0, stream>>>(T, MqkT, tvt, Zcat);
    gemm_out<<<dim3(12, 64), 256, 0, stream>>>(Zcat, Dcat, outp, proj_b);
}